// Round 1
// baseline (345.601 us; speedup 1.0000x reference)
//
#include <hip/hip_runtime.h>
#include <hip/hip_bf16.h>
#include <stdint.h>

#define B_ 4
#define S_ 2048
#define H_ 1024
#define NH_ 16
#define HD_ 64

typedef __attribute__((ext_vector_type(8))) short short8;
typedef __attribute__((ext_vector_type(4))) float f32x4;
typedef __attribute__((ext_vector_type(4))) unsigned short ushort4v;

__device__ __forceinline__ unsigned short f2bf(float f) {
  union { float f; unsigned u; } x; x.f = f;
  unsigned r = x.u + 0x7fffu + ((x.u >> 16) & 1u);
  return (unsigned short)(r >> 16);
}

#define ALDS16(g, l) \
  __builtin_amdgcn_global_load_lds((const __attribute__((address_space(1))) void*)(g), \
                                   (__attribute__((address_space(3))) void*)(l), 16, 0, 0)

// ---------------- input fp32 -> bf16 convert ----------------
__global__ __launch_bounds__(256) void cvt_in(
    const float* __restrict__ q, const float* __restrict__ k, const float* __restrict__ v,
    unsigned short* __restrict__ oq, unsigned short* __restrict__ ok2, unsigned short* __restrict__ ov) {
  const int z = blockIdx.z;
  const float* src = z == 0 ? q : (z == 1 ? k : v);
  unsigned short* dst = z == 0 ? oq : (z == 1 ? ok2 : ov);
  const size_t i = ((size_t)blockIdx.x * 256 + threadIdx.x) * 8;
  const f32x4 a = *reinterpret_cast<const f32x4*>(src + i);
  const f32x4 c = *reinterpret_cast<const f32x4*>(src + i + 4);
  short8 o;
#pragma unroll
  for (int j = 0; j < 4; ++j) { o[j] = (short)f2bf(a[j]); o[j + 4] = (short)f2bf(c[j]); }
  *reinterpret_cast<short8*>(dst + i) = o;
}

// ---------------- weight fp32 -> bf16 transpose (Wt[n][k] = W[k][n]) ----------------
__global__ __launch_bounds__(256) void cvt_w(
    const float* __restrict__ Wq, const float* __restrict__ Wk,
    const float* __restrict__ Wv, const float* __restrict__ Wo,
    unsigned short* __restrict__ wt) {
  __shared__ float tile[64][65];
  const int z = blockIdx.z;
  const float* W = z == 0 ? Wq : (z == 1 ? Wk : (z == 2 ? Wv : Wo));
  unsigned short* out = wt + (size_t)z * H_ * H_;
  const int t = threadIdx.x;
  const int r0 = blockIdx.y * 64, c0 = blockIdx.x * 64;
  const int tr = t >> 4, tc = (t & 15) * 4;
#pragma unroll
  for (int rr = 0; rr < 4; ++rr) {
    const int row = rr * 16 + tr;
    const f32x4 val = *reinterpret_cast<const f32x4*>(W + (size_t)(r0 + row) * H_ + c0 + tc);
#pragma unroll
    for (int j = 0; j < 4; ++j) tile[row][tc + j] = val[j];
  }
  __syncthreads();
#pragma unroll
  for (int rr = 0; rr < 4; ++rr) {
    const int c = rr * 16 + tr;
    ushort4v o;
#pragma unroll
    for (int j = 0; j < 4; ++j) o[j] = f2bf(tile[tc + j][c]);
    *reinterpret_cast<ushort4v*>(out + (size_t)(c0 + c) * H_ + r0 + tc) = o;
  }
}

// ---------------- GEMM: C[M,1024] = X[M,1024] @ Wt[1024,1024]^T (+bias) ----------------
// OUTMODE 0: bf16 head-split out [B,NH,S,HD].  OUTMODE 1: fp32 flat out [M,1024].
template <int OUTMODE>
__device__ __forceinline__ void gemm_body(
    const unsigned short* __restrict__ X, const unsigned short* __restrict__ Wt,
    const float* __restrict__ bias, unsigned short* __restrict__ obf,
    float* __restrict__ of32) {
  __shared__ unsigned short As[128 * 32];
  __shared__ unsigned short Bs[128 * 32];
  const int t = threadIdx.x;
  const int w = t >> 6, l = t & 63;
  const int lr = l & 15, lg = l >> 4;
  const int brow = blockIdx.x * 128, bcol = blockIdx.y * 128;
  const int wr = (w >> 1) * 64, wc = (w & 1) * 64;
  f32x4 acc[4][4] = {};
  const int i0 = t, i1 = t + 256;
  const int ar0 = i0 >> 2, ak0 = (i0 & 3) * 8;
  const int ar1 = i1 >> 2, ak1 = (i1 & 3) * 8;
  for (int kt = 0; kt < 1024; kt += 32) {
    ALDS16(X + (size_t)(brow + ar0) * 1024 + kt + ak0, As + i0 * 8);
    ALDS16(X + (size_t)(brow + ar1) * 1024 + kt + ak1, As + i1 * 8);
    ALDS16(Wt + (size_t)(bcol + ar0) * 1024 + kt + ak0, Bs + i0 * 8);
    ALDS16(Wt + (size_t)(bcol + ar1) * 1024 + kt + ak1, Bs + i1 * 8);
    __syncthreads();
    short8 af[4], bf[4];
#pragma unroll
    for (int m = 0; m < 4; ++m)
      af[m] = *reinterpret_cast<const short8*>(As + (wr + m * 16 + lr) * 32 + lg * 8);
#pragma unroll
    for (int n = 0; n < 4; ++n)
      bf[n] = *reinterpret_cast<const short8*>(Bs + (wc + n * 16 + lr) * 32 + lg * 8);
#pragma unroll
    for (int m = 0; m < 4; ++m)
#pragma unroll
      for (int n = 0; n < 4; ++n)
        acc[m][n] = __builtin_amdgcn_mfma_f32_16x16x32_bf16(af[m], bf[n], acc[m][n], 0, 0, 0);
    __syncthreads();
  }
#pragma unroll
  for (int m = 0; m < 4; ++m) {
#pragma unroll
    for (int n = 0; n < 4; ++n) {
#pragma unroll
      for (int r = 0; r < 4; ++r) {
        const int gr = brow + wr + m * 16 + lg * 4 + r;
        const int gc = bcol + wc + n * 16 + lr;
        const float val = acc[m][n][r] + bias[gc];
        if (OUTMODE == 0) {
          const int bb = gr >> 11, ss = gr & 2047, hh = gc >> 6, dd = gc & 63;
          obf[(((size_t)(bb * NH_ + hh)) * S_ + ss) * HD_ + dd] = f2bf(val);
        } else {
          of32[(size_t)gr * H_ + gc] = val;
        }
      }
    }
  }
}

__global__ __launch_bounds__(256) void gemm_qkv(
    const unsigned short* __restrict__ xq, const unsigned short* __restrict__ xk,
    const unsigned short* __restrict__ xv, const unsigned short* __restrict__ wt,
    const float* __restrict__ bq, const float* __restrict__ bk, const float* __restrict__ bv,
    unsigned short* __restrict__ qh, unsigned short* __restrict__ kh,
    unsigned short* __restrict__ vh) {
  const int z = blockIdx.z;
  const unsigned short* X = z == 0 ? xq : (z == 1 ? xk : xv);
  const unsigned short* W = wt + (size_t)z * H_ * H_;
  const float* bias = z == 0 ? bq : (z == 1 ? bk : bv);
  unsigned short* out = z == 0 ? qh : (z == 1 ? kh : vh);
  gemm_body<0>(X, W, bias, out, nullptr);
}

__global__ __launch_bounds__(256) void gemm_out(
    const unsigned short* __restrict__ ao, const unsigned short* __restrict__ wt,
    const float* __restrict__ bo, float* __restrict__ out) {
  gemm_body<1>(ao, wt, bo, nullptr, out);
}

// ---------------- V transpose per head: [bh][S][HD] -> [bh][HD][S] ----------------
__global__ __launch_bounds__(256) void vtrans(
    const unsigned short* __restrict__ vh, unsigned short* __restrict__ vt) {
  __shared__ unsigned short tile[64 * 72];
  const int bh = blockIdx.y;
  const int s0 = blockIdx.x * 64;
  const int t = threadIdx.x;
  const unsigned short* src = vh + (size_t)bh * S_ * HD_ + (size_t)s0 * HD_;
#pragma unroll
  for (int r = 0; r < 2; ++r) {
    const int i = t + r * 256;
    const int row = i >> 3, kc = i & 7;
    const short8 v = *reinterpret_cast<const short8*>(src + row * 64 + kc * 8);
    *reinterpret_cast<short8*>(tile + row * 72 + kc * 8) = v;
  }
  __syncthreads();
  unsigned short* dst = vt + (size_t)bh * HD_ * S_;
#pragma unroll
  for (int r = 0; r < 2; ++r) {
    const int i = t + r * 256;
    const int d = i >> 3, sc = i & 7;
    short8 o;
#pragma unroll
    for (int j = 0; j < 8; ++j) o[j] = (short)tile[(sc * 8 + j) * 72 + d];
    *reinterpret_cast<short8*>(dst + (size_t)d * S_ + s0 + sc * 8) = o;
  }
}

// ---------------- flash attention ----------------
// grid (32 q-tiles, 64 heads), 4 waves; wave handles 16 q-rows; KV tiles of 64.
__global__ __launch_bounds__(256) void attn_kernel(
    const unsigned short* __restrict__ qh, const unsigned short* __restrict__ kh,
    const unsigned short* __restrict__ vt, const float* __restrict__ mask,
    unsigned short* __restrict__ ao) {
  __shared__ unsigned short Ks[64 * 64];
  __shared__ unsigned short Vs[64 * 64];
  __shared__ unsigned short Ps[4 * 16 * 64];
  const int t = threadIdx.x, w = t >> 6, l = t & 63;
  const int lr = l & 15, lg = l >> 4;
  const int qt = blockIdx.x, bh = blockIdx.y;
  const int b = bh >> 4, h = bh & 15;
  const unsigned short* qptr = qh + (size_t)bh * S_ * HD_;
  const unsigned short* kptr = kh + (size_t)bh * S_ * HD_;
  const unsigned short* vptr = vt + (size_t)bh * HD_ * S_;
  const float* mptr = mask + (size_t)b * S_ * S_;
  const int qbase = qt * 64 + w * 16;

  short8 qf[2];
  {
    const unsigned short* qp = qptr + (size_t)(qbase + lr) * HD_ + lg * 8;
    qf[0] = *reinterpret_cast<const short8*>(qp);
    qf[1] = *reinterpret_cast<const short8*>(qp + 32);
  }

  float m_run[4] = {-1e30f, -1e30f, -1e30f, -1e30f};
  float l_run[4] = {0.f, 0.f, 0.f, 0.f};
  f32x4 acc_o[4] = {};
  unsigned short* pw = Ps + w * (16 * 64);

  for (int kv = 0; kv < S_; kv += 64) {
    // stage K,V tiles; LDS linear, global source pre-swizzled (kunit ^= row&7)
#pragma unroll
    for (int rch = 0; rch < 2; ++rch) {
      const int i = t + rch * 256;
      const int row = i >> 3;
      const int klog = (i & 7) ^ (row & 7);
      ALDS16(kptr + (size_t)(kv + row) * HD_ + klog * 8, Ks + i * 8);
    }
#pragma unroll
    for (int rch = 0; rch < 2; ++rch) {
      const int i = t + rch * 256;
      const int row = i >> 3;
      const int klog = (i & 7) ^ (row & 7);
      ALDS16(vptr + (size_t)row * S_ + kv + klog * 8, Vs + i * 8);
    }
    __syncthreads();

    // S = Q K^T
    float p[4][4];
#pragma unroll
    for (int n = 0; n < 4; ++n) {
      f32x4 sc = {};
#pragma unroll
      for (int kk = 0; kk < 2; ++kk) {
        const int krow = n * 16 + lr;
        const int kp = (kk * 4 + lg) ^ (krow & 7);
        const short8 kf = *reinterpret_cast<const short8*>(Ks + krow * 64 + kp * 8);
        sc = __builtin_amdgcn_mfma_f32_16x16x32_bf16(qf[kk], kf, sc, 0, 0, 0);
      }
#pragma unroll
      for (int r = 0; r < 4; ++r) p[n][r] = sc[r];
    }

    // scale + mask + online softmax (rows owned per lane-group: row = lg*4+r)
    float vmax[4] = {-3.0e38f, -3.0e38f, -3.0e38f, -3.0e38f};
#pragma unroll
    for (int r = 0; r < 4; ++r) {
      const int qrow = qbase + lg * 4 + r;
      const float* mrow = mptr + (size_t)qrow * S_ + kv;
#pragma unroll
      for (int n = 0; n < 4; ++n) {
        const float mval = mrow[n * 16 + lr];
        const float s = fmaf(mval, -1e9f, p[n][r] * 0.125f);
        p[n][r] = s;
        vmax[r] = fmaxf(vmax[r], s);
      }
    }
#pragma unroll
    for (int off = 1; off < 16; off <<= 1) {
#pragma unroll
      for (int r = 0; r < 4; ++r)
        vmax[r] = fmaxf(vmax[r], __shfl_xor(vmax[r], off));
    }
    float fac[4], rsum[4];
#pragma unroll
    for (int r = 0; r < 4; ++r) {
      const float mnew = fmaxf(m_run[r], vmax[r]);
      fac[r] = __expf(m_run[r] - mnew);
      m_run[r] = mnew;
      rsum[r] = 0.f;
    }
#pragma unroll
    for (int n = 0; n < 4; ++n)
#pragma unroll
      for (int r = 0; r < 4; ++r) {
        const float e = __expf(p[n][r] - m_run[r]);
        p[n][r] = e;
        rsum[r] += e;
      }
#pragma unroll
    for (int off = 1; off < 16; off <<= 1) {
#pragma unroll
      for (int r = 0; r < 4; ++r) rsum[r] += __shfl_xor(rsum[r], off);
    }
#pragma unroll
    for (int r = 0; r < 4; ++r) l_run[r] = l_run[r] * fac[r] + rsum[r];
#pragma unroll
    for (int d = 0; d < 4; ++d)
#pragma unroll
      for (int r = 0; r < 4; ++r) acc_o[d][r] *= fac[r];

    // P -> LDS bf16 (swizzled), then O += P V
#pragma unroll
    for (int n = 0; n < 4; ++n)
#pragma unroll
      for (int r = 0; r < 4; ++r) {
        const int row = lg * 4 + r;
        const int col = n * 16 + lr;
        const int kp = (col >> 3) ^ (row & 7);
        pw[row * 64 + kp * 8 + (col & 7)] = f2bf(p[n][r]);
      }
    short8 pf[2];
#pragma unroll
    for (int kk = 0; kk < 2; ++kk) {
      const int kp = (kk * 4 + lg) ^ (lr & 7);
      pf[kk] = *reinterpret_cast<const short8*>(pw + lr * 64 + kp * 8);
    }
#pragma unroll
    for (int d = 0; d < 4; ++d) {
#pragma unroll
      for (int kk = 0; kk < 2; ++kk) {
        const int vrow = d * 16 + lr;
        const int vp = (kk * 4 + lg) ^ (vrow & 7);
        const short8 vf = *reinterpret_cast<const short8*>(Vs + vrow * 64 + vp * 8);
        acc_o[d] = __builtin_amdgcn_mfma_f32_16x16x32_bf16(pf[kk], vf, acc_o[d], 0, 0, 0);
      }
    }
    __syncthreads();
  }

#pragma unroll
  for (int r = 0; r < 4; ++r) {
    const float inv = 1.f / l_run[r];
    const int qrow = qbase + lg * 4 + r;
    unsigned short* orow = ao + ((size_t)b * S_ + qrow) * H_ + h * HD_;
#pragma unroll
    for (int d = 0; d < 4; ++d)
      orow[d * 16 + lr] = f2bf(acc_o[d][r] * inv);
  }
}

extern "C" void kernel_launch(void* const* d_in, const int* in_sizes, int n_in,
                              void* d_out, int out_size, void* d_ws, size_t ws_size,
                              hipStream_t stream) {
  (void)in_sizes; (void)n_in; (void)out_size; (void)ws_size;
  const float* query = (const float*)d_in[0];
  const float* key_  = (const float*)d_in[1];
  const float* value = (const float*)d_in[2];
  const float* mask  = (const float*)d_in[3];
  const float* Wq = (const float*)d_in[4];
  const float* bq = (const float*)d_in[5];
  const float* Wk = (const float*)d_in[6];
  const float* bk = (const float*)d_in[7];
  const float* Wv = (const float*)d_in[8];
  const float* bv = (const float*)d_in[9];
  const float* Wo = (const float*)d_in[10];
  const float* bo = (const float*)d_in[11];
  float* out = (float*)d_out;

  char* ws = (char*)d_ws;
  const size_t MB16 = (size_t)1 << 24;  // 16,777,216 B = one [8192,1024] bf16 buffer
  unsigned short* XQ = (unsigned short*)(ws + 0 * MB16);
  unsigned short* XK = (unsigned short*)(ws + 1 * MB16);
  unsigned short* XV = (unsigned short*)(ws + 2 * MB16);
  unsigned short* QH = (unsigned short*)(ws + 3 * MB16);
  unsigned short* KH = (unsigned short*)(ws + 4 * MB16);
  unsigned short* VH = (unsigned short*)(ws + 5 * MB16);
  unsigned short* WT = (unsigned short*)(ws + 6 * MB16);  // 4 x 1024x1024 bf16 = 8 MB
  unsigned short* AO = XQ;  // reuse: XQ dead after gemm_qkv
  unsigned short* VT = XK;  // reuse: XK dead after gemm_qkv

  cvt_in<<<dim3(4096, 1, 3), 256, 0, stream>>>(query, key_, value, XQ, XK, XV);
  cvt_w<<<dim3(16, 16, 4), 256, 0, stream>>>(Wq, Wk, Wv, Wo, WT);
  gemm_qkv<<<dim3(64, 8, 3), 256, 0, stream>>>(XQ, XK, XV, WT, bq, bk, bv, QH, KH, VH);
  vtrans<<<dim3(32, 64), 256, 0, stream>>>(VH, VT);
  attn_kernel<<<dim3(32, 64), 256, 0, stream>>>(QH, KH, VT, mask, AO);
  gemm_out<<<dim3(64, 8, 1), 256, 0, stream>>>(AO, WT + 3 * (size_t)H_ * H_, bo, out);
}

// Round 2
// 331.574 us; speedup vs baseline: 1.0423x; 1.0423x over previous
//
#include <hip/hip_runtime.h>
#include <hip/hip_bf16.h>
#include <stdint.h>

#define B_ 4
#define S_ 2048
#define H_ 1024
#define NH_ 16
#define HD_ 64

typedef __attribute__((ext_vector_type(8))) short short8;
typedef __attribute__((ext_vector_type(4))) float f32x4;
typedef __attribute__((ext_vector_type(4))) unsigned short ushort4v;

__device__ __forceinline__ unsigned short f2bf(float f) {
  union { float f; unsigned u; } x; x.f = f;
  unsigned r = x.u + 0x7fffu + ((x.u >> 16) & 1u);
  return (unsigned short)(r >> 16);
}

__device__ __forceinline__ unsigned short f2bf_trunc(float f) {
  union { float f; unsigned u; } x; x.f = f;
  return (unsigned short)(x.u >> 16);
}

#define ALDS16(g, l) \
  __builtin_amdgcn_global_load_lds((const __attribute__((address_space(1))) void*)(g), \
                                   (__attribute__((address_space(3))) void*)(l), 16, 0, 0)

// ---------------- input fp32 -> bf16 convert ----------------
__global__ __launch_bounds__(256) void cvt_in(
    const float* __restrict__ q, const float* __restrict__ k, const float* __restrict__ v,
    unsigned short* __restrict__ oq, unsigned short* __restrict__ ok2, unsigned short* __restrict__ ov) {
  const int z = blockIdx.z;
  const float* src = z == 0 ? q : (z == 1 ? k : v);
  unsigned short* dst = z == 0 ? oq : (z == 1 ? ok2 : ov);
  const size_t i = ((size_t)blockIdx.x * 256 + threadIdx.x) * 8;
  const f32x4 a = *reinterpret_cast<const f32x4*>(src + i);
  const f32x4 c = *reinterpret_cast<const f32x4*>(src + i + 4);
  short8 o;
#pragma unroll
  for (int j = 0; j < 4; ++j) { o[j] = (short)f2bf(a[j]); o[j + 4] = (short)f2bf(c[j]); }
  *reinterpret_cast<short8*>(dst + i) = o;
}

// ---------------- weight fp32 -> bf16 transpose (Wt[n][k] = W[k][n]) ----------------
__global__ __launch_bounds__(256) void cvt_w(
    const float* __restrict__ Wq, const float* __restrict__ Wk,
    const float* __restrict__ Wv, const float* __restrict__ Wo,
    unsigned short* __restrict__ wt) {
  __shared__ float tile[64][65];
  const int z = blockIdx.z;
  const float* W = z == 0 ? Wq : (z == 1 ? Wk : (z == 2 ? Wv : Wo));
  unsigned short* out = wt + (size_t)z * H_ * H_;
  const int t = threadIdx.x;
  const int r0 = blockIdx.y * 64, c0 = blockIdx.x * 64;
  const int tr = t >> 4, tc = (t & 15) * 4;
#pragma unroll
  for (int rr = 0; rr < 4; ++rr) {
    const int row = rr * 16 + tr;
    const f32x4 val = *reinterpret_cast<const f32x4*>(W + (size_t)(r0 + row) * H_ + c0 + tc);
#pragma unroll
    for (int j = 0; j < 4; ++j) tile[row][tc + j] = val[j];
  }
  __syncthreads();
#pragma unroll
  for (int rr = 0; rr < 4; ++rr) {
    const int c = rr * 16 + tr;
    ushort4v o;
#pragma unroll
    for (int j = 0; j < 4; ++j) o[j] = f2bf(tile[tc + j][c]);
    *reinterpret_cast<ushort4v*>(out + (size_t)(c0 + c) * H_ + r0 + tc) = o;
  }
}

// ---------------- GEMM: C[M,1024] = X[M,1024] @ Wt[1024,1024]^T (+bias) ----------------
template <int OUTMODE>
__device__ __forceinline__ void gemm_body(
    const unsigned short* __restrict__ X, const unsigned short* __restrict__ Wt,
    const float* __restrict__ bias, unsigned short* __restrict__ obf,
    float* __restrict__ of32) {
  __shared__ unsigned short As[128 * 32];
  __shared__ unsigned short Bs[128 * 32];
  const int t = threadIdx.x;
  const int w = t >> 6, l = t & 63;
  const int lr = l & 15, lg = l >> 4;
  const int brow = blockIdx.x * 128, bcol = blockIdx.y * 128;
  const int wr = (w >> 1) * 64, wc = (w & 1) * 64;
  f32x4 acc[4][4] = {};
  const int i0 = t, i1 = t + 256;
  const int ar0 = i0 >> 2, ak0 = (i0 & 3) * 8;
  const int ar1 = i1 >> 2, ak1 = (i1 & 3) * 8;
  for (int kt = 0; kt < 1024; kt += 32) {
    ALDS16(X + (size_t)(brow + ar0) * 1024 + kt + ak0, As + i0 * 8);
    ALDS16(X + (size_t)(brow + ar1) * 1024 + kt + ak1, As + i1 * 8);
    ALDS16(Wt + (size_t)(bcol + ar0) * 1024 + kt + ak0, Bs + i0 * 8);
    ALDS16(Wt + (size_t)(bcol + ar1) * 1024 + kt + ak1, Bs + i1 * 8);
    __syncthreads();
    short8 af[4], bf[4];
#pragma unroll
    for (int m = 0; m < 4; ++m)
      af[m] = *reinterpret_cast<const short8*>(As + (wr + m * 16 + lr) * 32 + lg * 8);
#pragma unroll
    for (int n = 0; n < 4; ++n)
      bf[n] = *reinterpret_cast<const short8*>(Bs + (wc + n * 16 + lr) * 32 + lg * 8);
#pragma unroll
    for (int m = 0; m < 4; ++m)
#pragma unroll
      for (int n = 0; n < 4; ++n)
        acc[m][n] = __builtin_amdgcn_mfma_f32_16x16x32_bf16(af[m], bf[n], acc[m][n], 0, 0, 0);
    __syncthreads();
  }
#pragma unroll
  for (int m = 0; m < 4; ++m) {
#pragma unroll
    for (int n = 0; n < 4; ++n) {
#pragma unroll
      for (int r = 0; r < 4; ++r) {
        const int gr = brow + wr + m * 16 + lg * 4 + r;
        const int gc = bcol + wc + n * 16 + lr;
        const float val = acc[m][n][r] + bias[gc];
        if (OUTMODE == 0) {
          const int bb = gr >> 11, ss = gr & 2047, hh = gc >> 6, dd = gc & 63;
          obf[(((size_t)(bb * NH_ + hh)) * S_ + ss) * HD_ + dd] = f2bf(val);
        } else {
          of32[(size_t)gr * H_ + gc] = val;
        }
      }
    }
  }
}

__global__ __launch_bounds__(256) void gemm_qkv(
    const unsigned short* __restrict__ xq, const unsigned short* __restrict__ xk,
    const unsigned short* __restrict__ xv, const unsigned short* __restrict__ wt,
    const float* __restrict__ bq, const float* __restrict__ bk, const float* __restrict__ bv,
    unsigned short* __restrict__ qh, unsigned short* __restrict__ kh,
    unsigned short* __restrict__ vh) {
  const int z = blockIdx.z;
  const unsigned short* X = z == 0 ? xq : (z == 1 ? xk : xv);
  const unsigned short* W = wt + (size_t)z * H_ * H_;
  const float* bias = z == 0 ? bq : (z == 1 ? bk : bv);
  unsigned short* out = z == 0 ? qh : (z == 1 ? kh : vh);
  gemm_body<0>(X, W, bias, out, nullptr);
}

__global__ __launch_bounds__(256) void gemm_out(
    const unsigned short* __restrict__ ao, const unsigned short* __restrict__ wt,
    const float* __restrict__ bo, float* __restrict__ out) {
  gemm_body<1>(ao, wt, bo, nullptr, out);
}

// ---------------- V transpose per head: [bh][S][HD] -> [bh][HD][S] ----------------
__global__ __launch_bounds__(256) void vtrans(
    const unsigned short* __restrict__ vh, unsigned short* __restrict__ vt) {
  __shared__ unsigned short tile[64 * 72];
  const int bh = blockIdx.y;
  const int s0 = blockIdx.x * 64;
  const int t = threadIdx.x;
  const unsigned short* src = vh + (size_t)bh * S_ * HD_ + (size_t)s0 * HD_;
#pragma unroll
  for (int r = 0; r < 2; ++r) {
    const int i = t + r * 256;
    const int row = i >> 3, kc = i & 7;
    const short8 v = *reinterpret_cast<const short8*>(src + row * 64 + kc * 8);
    *reinterpret_cast<short8*>(tile + row * 72 + kc * 8) = v;
  }
  __syncthreads();
  unsigned short* dst = vt + (size_t)bh * HD_ * S_;
#pragma unroll
  for (int r = 0; r < 2; ++r) {
    const int i = t + r * 256;
    const int d = i >> 3, sc = i & 7;
    short8 o;
#pragma unroll
    for (int j = 0; j < 8; ++j) o[j] = (short)tile[(sc * 8 + j) * 72 + d];
    *reinterpret_cast<short8*>(dst + (size_t)d * S_ + s0 + sc * 8) = o;
  }
}

// ---------------- flash attention (2-phase dbuf pipeline) ----------------
// grid (32 q-tiles, 64 heads), 4 waves; wave handles 16 q-rows; KV tiles of 64.
#define SCL_LOG2E 0.1803368801111244f      /* 0.125 * log2(e) */
#define MBIG (-1.4426950408889634e9f)      /* -1e9 * log2(e)  */

__global__ __launch_bounds__(256) void attn_kernel(
    const unsigned short* __restrict__ qh, const unsigned short* __restrict__ kh,
    const unsigned short* __restrict__ vt, const float* __restrict__ mask,
    unsigned short* __restrict__ ao) {
  __shared__ unsigned short Ks[2][64 * 64];
  __shared__ unsigned short Vs[2][64 * 64];
  __shared__ unsigned short Ps[4][16 * 64];
  const int t = threadIdx.x, w = t >> 6, l = t & 63;
  const int lr = l & 15, lg = l >> 4;
  const int qt = blockIdx.x, bh = blockIdx.y;
  const int b = bh >> 4, h = bh & 15;
  const unsigned short* qptr = qh + (size_t)bh * S_ * HD_;
  const unsigned short* kptr = kh + (size_t)bh * S_ * HD_;
  const unsigned short* vptr = vt + (size_t)bh * HD_ * S_;
  const float* mptr = mask + (size_t)b * S_ * S_;
  const int qbase = qt * 64 + w * 16;

  short8 qf[2];
  {
    const unsigned short* qp = qptr + (size_t)(qbase + lr) * HD_ + lg * 8;
    qf[0] = *reinterpret_cast<const short8*>(qp);
    qf[1] = *reinterpret_cast<const short8*>(qp + 32);
  }
  short8 ones;
#pragma unroll
  for (int j = 0; j < 8; ++j) ones[j] = (short)0x3F80;  // bf16 1.0

  // staging indices (global source pre-swizzled so LDS stays linear)
  const int si0 = t, si1 = t + 256;
  const int srow0 = si0 >> 3, sk0 = ((si0 & 7) ^ (srow0 & 7)) * 8;
  const int srow1 = si1 >> 3, sk1 = ((si1 & 7) ^ (srow1 & 7)) * 8;

  // prologue: stage tile 0 into buffer 0
  ALDS16(kptr + (size_t)srow0 * HD_ + sk0, Ks[0] + si0 * 8);
  ALDS16(kptr + (size_t)srow1 * HD_ + sk1, Ks[0] + si1 * 8);
  ALDS16(vptr + (size_t)srow0 * S_ + sk0, Vs[0] + si0 * 8);
  ALDS16(vptr + (size_t)srow1 * S_ + sk1, Vs[0] + si1 * 8);
  __syncthreads();

  float m_run[4] = {-1e30f, -1e30f, -1e30f, -1e30f};
  f32x4 acc_o[4] = {};
  f32x4 acc_l = {};
  unsigned short* pw = Ps[w];
  int cur = 0;

  for (int kv = 0; kv < S_; kv += 64) {
    // mask loads for THIS tile (issued early; consumed after QK^T)
    float mreg[4][4];
#pragma unroll
    for (int r = 0; r < 4; ++r) {
      const float* mrow = mptr + (size_t)(qbase + lg * 4 + r) * S_ + kv;
#pragma unroll
      for (int n = 0; n < 4; ++n) mreg[n][r] = mrow[n * 16 + lr] * MBIG;
    }

    // stage NEXT tile into the other buffer (drained by end-of-iter barrier)
    const int nkv = (kv + 64 < S_) ? kv + 64 : 0;
    ALDS16(kptr + (size_t)(nkv + srow0) * HD_ + sk0, Ks[cur ^ 1] + si0 * 8);
    ALDS16(kptr + (size_t)(nkv + srow1) * HD_ + sk1, Ks[cur ^ 1] + si1 * 8);
    ALDS16(vptr + (size_t)srow0 * S_ + nkv + sk0, Vs[cur ^ 1] + si0 * 8);
    ALDS16(vptr + (size_t)srow1 * S_ + nkv + sk1, Vs[cur ^ 1] + si1 * 8);

    // S = Q K^T  (scores in log2 domain: arg = s*scale*log2e + mask_pre)
    float p[4][4];
#pragma unroll
    for (int n = 0; n < 4; ++n) {
      f32x4 sc = {};
#pragma unroll
      for (int kk = 0; kk < 2; ++kk) {
        const int krow = n * 16 + lr;
        const int kp = (kk * 4 + lg) ^ (krow & 7);
        const short8 kf = *reinterpret_cast<const short8*>(Ks[cur] + krow * 64 + kp * 8);
        sc = __builtin_amdgcn_mfma_f32_16x16x32_bf16(qf[kk], kf, sc, 0, 0, 0);
      }
#pragma unroll
      for (int r = 0; r < 4; ++r) p[n][r] = fmaf(sc[r], SCL_LOG2E, mreg[n][r]);
    }

    // online softmax: row max (in-reg + 16-lane shuffle), exp2, rescale
    float vmax[4];
#pragma unroll
    for (int r = 0; r < 4; ++r)
      vmax[r] = fmaxf(fmaxf(p[0][r], p[1][r]), fmaxf(p[2][r], p[3][r]));
#pragma unroll
    for (int off = 1; off < 16; off <<= 1) {
#pragma unroll
      for (int r = 0; r < 4; ++r)
        vmax[r] = fmaxf(vmax[r], __shfl_xor(vmax[r], off));
    }
    float fac[4];
#pragma unroll
    for (int r = 0; r < 4; ++r) {
      const float mnew = fmaxf(m_run[r], vmax[r]);
      fac[r] = __builtin_amdgcn_exp2f(m_run[r] - mnew);
      m_run[r] = mnew;
    }
#pragma unroll
    for (int n = 0; n < 4; ++n)
#pragma unroll
      for (int r = 0; r < 4; ++r)
        p[n][r] = __builtin_amdgcn_exp2f(p[n][r] - m_run[r]);
#pragma unroll
    for (int d = 0; d < 4; ++d)
#pragma unroll
      for (int r = 0; r < 4; ++r) acc_o[d][r] *= fac[r];
#pragma unroll
    for (int r = 0; r < 4; ++r) acc_l[r] *= fac[r];

    // P -> LDS bf16 (truncated; numerator/denominator use identical values)
#pragma unroll
    for (int n = 0; n < 4; ++n)
#pragma unroll
      for (int r = 0; r < 4; ++r) {
        const int row = lg * 4 + r;
        const int col = n * 16 + lr;
        const int kp = (col >> 3) ^ (row & 7);
        pw[row * 64 + kp * 8 + (col & 7)] = f2bf_trunc(p[n][r]);
      }
    short8 pf[2];
#pragma unroll
    for (int kk = 0; kk < 2; ++kk) {
      const int kp = (kk * 4 + lg) ^ (lr & 7);
      pf[kk] = *reinterpret_cast<const short8*>(pw + lr * 64 + kp * 8);
    }
    // row-sum via MFMA with ones-B (l uses exactly the bf16 P the PV uses)
#pragma unroll
    for (int kk = 0; kk < 2; ++kk)
      acc_l = __builtin_amdgcn_mfma_f32_16x16x32_bf16(pf[kk], ones, acc_l, 0, 0, 0);
    // O += P V
#pragma unroll
    for (int d = 0; d < 4; ++d) {
#pragma unroll
      for (int kk = 0; kk < 2; ++kk) {
        const int vrow = d * 16 + lr;
        const int vp = (kk * 4 + lg) ^ (vrow & 7);
        const short8 vf = *reinterpret_cast<const short8*>(Vs[cur] + vrow * 64 + vp * 8);
        acc_o[d] = __builtin_amdgcn_mfma_f32_16x16x32_bf16(pf[kk], vf, acc_o[d], 0, 0, 0);
      }
    }
    __syncthreads();  // drains stage(t+1) vmem + everyone done reading buf[cur]
    cur ^= 1;
  }

#pragma unroll
  for (int r = 0; r < 4; ++r) {
    const float inv = __builtin_amdgcn_rcpf(acc_l[r]);
    const int qrow = qbase + lg * 4 + r;
    unsigned short* orow = ao + ((size_t)b * S_ + qrow) * H_ + h * HD_;
#pragma unroll
    for (int d = 0; d < 4; ++d)
      orow[d * 16 + lr] = f2bf(acc_o[d][r] * inv);
  }
}

extern "C" void kernel_launch(void* const* d_in, const int* in_sizes, int n_in,
                              void* d_out, int out_size, void* d_ws, size_t ws_size,
                              hipStream_t stream) {
  (void)in_sizes; (void)n_in; (void)out_size; (void)ws_size;
  const float* query = (const float*)d_in[0];
  const float* key_  = (const float*)d_in[1];
  const float* value = (const float*)d_in[2];
  const float* mask  = (const float*)d_in[3];
  const float* Wq = (const float*)d_in[4];
  const float* bq = (const float*)d_in[5];
  const float* Wk = (const float*)d_in[6];
  const float* bk = (const float*)d_in[7];
  const float* Wv = (const float*)d_in[8];
  const float* bv = (const float*)d_in[9];
  const float* Wo = (const float*)d_in[10];
  const float* bo = (const float*)d_in[11];
  float* out = (float*)d_out;

  char* ws = (char*)d_ws;
  const size_t MB16 = (size_t)1 << 24;
  unsigned short* XQ = (unsigned short*)(ws + 0 * MB16);
  unsigned short* XK = (unsigned short*)(ws + 1 * MB16);
  unsigned short* XV = (unsigned short*)(ws + 2 * MB16);
  unsigned short* QH = (unsigned short*)(ws + 3 * MB16);
  unsigned short* KH = (unsigned short*)(ws + 4 * MB16);
  unsigned short* VH = (unsigned short*)(ws + 5 * MB16);
  unsigned short* WT = (unsigned short*)(ws + 6 * MB16);
  unsigned short* AO = XQ;  // reuse: XQ dead after gemm_qkv
  unsigned short* VT = XK;  // reuse: XK dead after gemm_qkv

  cvt_in<<<dim3(4096, 1, 3), 256, 0, stream>>>(query, key_, value, XQ, XK, XV);
  cvt_w<<<dim3(16, 16, 4), 256, 0, stream>>>(Wq, Wk, Wv, Wo, WT);
  gemm_qkv<<<dim3(64, 8, 3), 256, 0, stream>>>(XQ, XK, XV, WT, bq, bk, bv, QH, KH, VH);
  vtrans<<<dim3(32, 64), 256, 0, stream>>>(VH, VT);
  attn_kernel<<<dim3(32, 64), 256, 0, stream>>>(QH, KH, VT, mask, AO);
  gemm_out<<<dim3(64, 8, 1), 256, 0, stream>>>(AO, WT + 3 * (size_t)H_ * H_, bo, out);
}